// Round 2
// baseline (2099.739 us; speedup 1.0000x reference)
//
#include <hip/hip_runtime.h>
#include <hip/hip_bf16.h>

#define NN 10000
#define INDIM 256
#define HIDDIM 64

typedef __hip_bfloat16 bf16;

// ---------------- runtime dtype sniffing ----------------
// flags[0]: 1 if float tensors are bf16, 0 if float32
// flags[1]: 1 if edge_index is int64, 0 if int32
__global__ void k_sniff(const unsigned* __restrict__ xw, const unsigned* __restrict__ ew,
                        int* __restrict__ flags) {
    if (threadIdx.x == 0 && blockIdx.x == 0) {
        int c = 0;
        for (int j = 0; j < 256; ++j) {
            unsigned e = (xw[j] >> 7) & 0xFF;   // exponent field of low-half-as-bf16
            c += (e >= 0x74 && e <= 0x85);      // |v| in [2^-11, 2^6]: ~99% for bf16 N(0,1), ~7% for f32 mantissa bits
        }
        flags[0] = (c >= 128);
        int z = 0;
        for (int j = 0; j < 128; ++j) z += (ew[2 * j + 1] == 0u);  // int64 high words
        flags[1] = (z >= 64);
    }
}

__global__ void k_cvt(const void* __restrict__ in, float* __restrict__ out, int n,
                      const int* __restrict__ flags) {
    int i = blockIdx.x * 256 + threadIdx.x;
    if (i >= n) return;
    if (flags[0]) out[i] = __bfloat162float(((const bf16*)in)[i]);
    else          out[i] = ((const float*)in)[i];
}

__global__ void k_cvt_idx(const void* __restrict__ ei, int* __restrict__ s32,
                          int* __restrict__ d32, int E, const int* __restrict__ flags) {
    int e = blockIdx.x * 256 + threadIdx.x;
    if (e >= E) return;
    if (flags[1]) {
        const long long* p = (const long long*)ei;
        s32[e] = (int)p[e]; d32[e] = (int)p[e + E];
    } else {
        const int* p = (const int*)ei;
        s32[e] = p[e]; d32[e] = p[e + E];
    }
}

// ---------------- gcn_norm ----------------

__global__ void k_init_deg(float* deg) {
    int i = blockIdx.x * 256 + threadIdx.x;
    if (i < NN) deg[i] = 1.0f;   // self-loop weight
}

__global__ void k_edge_deg(const int* __restrict__ src, const int* __restrict__ dst,
                           float* __restrict__ deg, int E) {
    int e = blockIdx.x * 256 + threadIdx.x;
    if (e < E) {
        int s = src[e], d = dst[e];
        if (s != d) atomicAdd(&deg[d], 1.0f);   // existing self-loops get weight 0
    }
}

__global__ void k_dinv(float* deg, float* selfn) {
    int i = blockIdx.x * 256 + threadIdx.x;
    if (i < NN) {
        float dv = 1.0f / sqrtf(deg[i]);   // deg >= 1 always
        deg[i] = dv;                       // deg buffer becomes dinv
        selfn[i] = dv * dv;
    }
}

__global__ void k_edge_norm(const int* __restrict__ src, const int* __restrict__ dst,
                            const float* __restrict__ dinv, float* __restrict__ nrm, int E) {
    int e = blockIdx.x * 256 + threadIdx.x;
    if (e < E) {
        int s = src[e], d = dst[e];
        nrm[e] = (s != d) ? dinv[s] * dinv[d] : 0.0f;
    }
}

// ---------------- dense xw = A @ W (fp32) ----------------
// block (64,4): wave = one row i, 64 consecutive j

template <int K, int NOUT>
__global__ void k_gemm(const float* __restrict__ A, const float* __restrict__ W,
                       float* __restrict__ out) {
    int j = blockIdx.x * 64 + threadIdx.x;
    int i = blockIdx.y * 4 + threadIdx.y;
    const float* arow = A + (size_t)i * K;
    float acc = 0.0f;
#pragma unroll 8
    for (int k = 0; k < K; ++k)
        acc = fmaf(arow[k], W[k * NOUT + j], acc);
    out[(size_t)i * NOUT + j] = acc;
}

// ---------------- aggregation ----------------

template <int F>
__global__ void k_agg_init(const float* __restrict__ xw, const float* __restrict__ selfn,
                           float* __restrict__ agg) {
    int t = blockIdx.x * 256 + threadIdx.x;
    int i = t / F;
    agg[t] = selfn[i] * xw[t];
}

template <int F>
__global__ void k_scatter(const int* __restrict__ src, const int* __restrict__ dst,
                          const float* __restrict__ nrm, const float* __restrict__ xw,
                          float* __restrict__ agg, int E) {
    int e = blockIdx.x * 4 + (threadIdx.x >> 6);
    int lane = threadIdx.x & 63;
    if (e < E) {
        float w = nrm[e];
        if (w != 0.0f) {
            const float* xs = xw + (size_t)src[e] * F;
            float* ad = agg + (size_t)dst[e] * F;
#pragma unroll
            for (int r = 0; r < F / 64; ++r) {
                int f = r * 64 + lane;
                atomicAdd(ad + f, w * xs[f]);
            }
        }
    }
}

template <int F, bool RELU>
__global__ void k_finalize_f32(const float* __restrict__ agg, const float* __restrict__ b,
                               float* __restrict__ out) {
    int t = blockIdx.x * 256 + threadIdx.x;
    float v = agg[t] + b[t & (F - 1)];
    if (RELU) v = fmaxf(v, 0.0f);
    out[t] = v;
}

// final x_ write: dtype chosen at runtime
__global__ void k_finalize_out(const float* __restrict__ agg, const float* __restrict__ b,
                               void* __restrict__ out, const int* __restrict__ flags) {
    int t = blockIdx.x * 256 + threadIdx.x;
    float v = agg[t] + b[t & 255];
    if (flags[0]) ((bf16*)out)[t] = __float2bfloat16(v);
    else          ((float*)out)[t] = v;
}

// ---------------- adj = hs @ hs^T (fp32, 64x64 tile, 4x4 microtile) ----------------

__global__ __launch_bounds__(256) void k_adj(const float* __restrict__ hs,
                                             void* __restrict__ d_out,
                                             const int* __restrict__ flags) {
    __shared__ __align__(16) float As[64][36];
    __shared__ __align__(16) float Bs[64][36];

    int tid = threadIdx.x;
    int lr = tid >> 2;
    int lk = (tid & 3) * 8;
    int ty = tid >> 4;
    int tx = tid & 15;
    int row0 = blockIdx.y * 64, col0 = blockIdx.x * 64;
    int obf = flags[0];

    float acc[4][4] = {};
    for (int k0 = 0; k0 < INDIM; k0 += 32) {
        float4 a0 = make_float4(0.f, 0.f, 0.f, 0.f), a1 = a0, b0 = a0, b1 = a0;
        int ar = row0 + lr, br = col0 + lr;
        if (ar < NN) {
            const float4* p = (const float4*)(hs + (size_t)ar * INDIM + k0 + lk);
            a0 = p[0]; a1 = p[1];
        }
        if (br < NN) {
            const float4* p = (const float4*)(hs + (size_t)br * INDIM + k0 + lk);
            b0 = p[0]; b1 = p[1];
        }
        __syncthreads();
        *(float4*)&As[lr][lk] = a0; *(float4*)&As[lr][lk + 4] = a1;
        *(float4*)&Bs[lr][lk] = b0; *(float4*)&Bs[lr][lk + 4] = b1;
        __syncthreads();
#pragma unroll
        for (int kt = 0; kt < 32; ++kt) {
            float av[4], bv[4];
#pragma unroll
            for (int u = 0; u < 4; ++u) av[u] = As[ty * 4 + u][kt];
#pragma unroll
            for (int v = 0; v < 4; ++v) bv[v] = Bs[tx + 16 * v][kt];
#pragma unroll
            for (int u = 0; u < 4; ++u)
#pragma unroll
                for (int v = 0; v < 4; ++v)
                    acc[u][v] = fmaf(av[u], bv[v], acc[u][v]);
        }
    }
    bf16*  ob = (bf16*)d_out + (size_t)NN * INDIM;
    float* of = (float*)d_out + (size_t)NN * INDIM;
#pragma unroll
    for (int u = 0; u < 4; ++u) {
        int i = row0 + ty * 4 + u;
        if (i >= NN) continue;
#pragma unroll
        for (int v = 0; v < 4; ++v) {
            int j = col0 + tx + 16 * v;
            if (j < NN) {
                if (obf) ob[(size_t)i * NN + j] = __float2bfloat16(acc[u][v]);
                else     of[(size_t)i * NN + j] = acc[u][v];
            }
        }
    }
}

// ---------------- driver ----------------

extern "C" void kernel_launch(void* const* d_in, const int* in_sizes, int n_in,
                              void* d_out, int out_size, void* d_ws, size_t ws_size,
                              hipStream_t stream) {
    const void* x_raw  = d_in[0];
    const void* ei_raw = d_in[1];

    const int E = in_sizes[1] / 2;

    // ---- d_ws layout (floats; ~13.8 MB total) ----
    int*   flags = (int*)d_ws;
    float* wsf   = (float*)d_ws;
    float* deg   = wsf + 16;        // 10000 (reserve 10240)
    float* selfn = wsf + 10256;     // 10000 (reserve 10240)
    float* nrm   = wsf + 20496;     // E (reserve 327680)
    int*   s32   = (int*)(wsf + 348176);   // E
    int*   d32   = (int*)(wsf + 668176);   // E
    float* w32   = wsf + 988176;    // 58048 fp32 weights/biases
    float* hs    = wsf + 1046560;   // NN*256 (survives k_adj)

    float* encW1 = w32 + 0;
    float* encb1 = w32 + 16384;
    float* encW2 = w32 + 16448;
    float* encb2 = w32 + 20544;
    float* attW1 = w32 + 20608;
    float* attb1 = w32 + 24704;
    float* attW2 = w32 + 24768;
    float* attb2 = w32 + 41152;
    float* stW   = w32 + 41408;
    float* stb   = w32 + 57792;

    // ---- large scratch inside adj output region (overwritten last by k_adj) ----
    float* osc  = (float*)((char*)d_out + 16000000);  // 16 MB byte offset, 16B aligned
    float* x32  = osc;                 // NN*256
    float* bufA = osc + 2560000;       // NN*256
    float* bufB = osc + 5120000;       // NN*256
    float* h1   = osc + 7680000;       // NN*64
    float* h2   = osc + 8320000;       // NN*64
    float* a1   = osc + 8960000;       // NN*64

    int eb  = (E + 255) / 256;
    int ewb = (E + 3) / 4;

    k_sniff<<<1, 64, 0, stream>>>((const unsigned*)x_raw, (const unsigned*)ei_raw, flags);

    // convert inputs to fp32 / int32
    k_cvt<<<10000, 256, 0, stream>>>(x_raw, x32, NN * INDIM, flags);
    k_cvt<<<64, 256, 0, stream>>>(d_in[2],  encW1, 16384, flags);
    k_cvt<<<1, 256, 0, stream>>>(d_in[3],   encb1, 64, flags);
    k_cvt<<<16, 256, 0, stream>>>(d_in[4],  encW2, 4096, flags);
    k_cvt<<<1, 256, 0, stream>>>(d_in[5],   encb2, 64, flags);
    k_cvt<<<16, 256, 0, stream>>>(d_in[6],  attW1, 4096, flags);
    k_cvt<<<1, 256, 0, stream>>>(d_in[7],   attb1, 64, flags);
    k_cvt<<<64, 256, 0, stream>>>(d_in[8],  attW2, 16384, flags);
    k_cvt<<<1, 256, 0, stream>>>(d_in[9],   attb2, 256, flags);
    k_cvt<<<64, 256, 0, stream>>>(d_in[10], stW, 16384, flags);
    k_cvt<<<1, 256, 0, stream>>>(d_in[11],  stb, 256, flags);
    k_cvt_idx<<<eb, 256, 0, stream>>>(ei_raw, s32, d32, E, flags);

    // gcn_norm
    k_init_deg<<<40, 256, 0, stream>>>(deg);
    k_edge_deg<<<eb, 256, 0, stream>>>(s32, d32, deg, E);
    k_dinv<<<40, 256, 0, stream>>>(deg, selfn);
    k_edge_norm<<<eb, 256, 0, stream>>>(s32, d32, deg, nrm, E);

    // conv1: x32 @ encW1 -> relu -> h1
    k_gemm<256, 64><<<dim3(1, 2500), dim3(64, 4), 0, stream>>>(x32, encW1, bufA);
    k_agg_init<64><<<2500, 256, 0, stream>>>(bufA, selfn, bufB);
    k_scatter<64><<<ewb, 256, 0, stream>>>(s32, d32, nrm, bufA, bufB, E);
    k_finalize_f32<64, true><<<2500, 256, 0, stream>>>(bufB, encb1, h1);

    // conv2: h1 @ encW2 -> h2
    k_gemm<64, 64><<<dim3(1, 2500), dim3(64, 4), 0, stream>>>(h1, encW2, bufA);
    k_agg_init<64><<<2500, 256, 0, stream>>>(bufA, selfn, bufB);
    k_scatter<64><<<ewb, 256, 0, stream>>>(s32, d32, nrm, bufA, bufB, E);
    k_finalize_f32<64, false><<<2500, 256, 0, stream>>>(bufB, encb2, h2);

    // conv3: h2 @ attW1 -> relu -> a1
    k_gemm<64, 64><<<dim3(1, 2500), dim3(64, 4), 0, stream>>>(h2, attW1, bufA);
    k_agg_init<64><<<2500, 256, 0, stream>>>(bufA, selfn, bufB);
    k_scatter<64><<<ewb, 256, 0, stream>>>(s32, d32, nrm, bufA, bufB, E);
    k_finalize_f32<64, true><<<2500, 256, 0, stream>>>(bufB, attb1, a1);

    // conv4: a1 @ attW2 -> x_ (runtime out dtype)
    k_gemm<64, 256><<<dim3(4, 2500), dim3(64, 4), 0, stream>>>(a1, attW2, bufA);
    k_agg_init<256><<<10000, 256, 0, stream>>>(bufA, selfn, bufB);
    k_scatter<256><<<ewb, 256, 0, stream>>>(s32, d32, nrm, bufA, bufB, E);
    k_finalize_out<<<10000, 256, 0, stream>>>(bufB, attb2, d_out, flags);

    // conv5: h2 @ stW -> hs (fp32, in d_ws)
    k_gemm<64, 256><<<dim3(4, 2500), dim3(64, 4), 0, stream>>>(h2, stW, bufA);
    k_agg_init<256><<<10000, 256, 0, stream>>>(bufA, selfn, bufB);
    k_scatter<256><<<ewb, 256, 0, stream>>>(s32, d32, nrm, bufA, bufB, E);
    k_finalize_f32<256, false><<<10000, 256, 0, stream>>>(bufB, stb, hs);

    // adj = hs @ hs^T
    k_adj<<<dim3(157, 157), 256, 0, stream>>>(hs, d_out, flags);
}